// Round 3
// baseline (680.820 us; speedup 1.0000x reference)
//
#include <hip/hip_runtime.h>
#include <hip/hip_bf16.h>

#define D_OUT 64
#define K_DIM 512

using short8  = __attribute__((ext_vector_type(8))) short;
using floatx4 = __attribute__((ext_vector_type(4))) float;

__device__ inline unsigned short f32_to_bf16(float f) {
    unsigned int u = __float_as_uint(f);
    u += 0x7FFFu + ((u >> 16) & 1u);   // round-to-nearest-even
    return (unsigned short)(u >> 16);
}

// ---------------------------------------------------------------------------
// zero float buffer (float4-vectorized)
__global__ void zero4_kernel(float4* __restrict__ p, int n4) {
    int i = blockIdx.x * blockDim.x + threadIdx.x;
    if (i < n4) p[i] = make_float4(0.f, 0.f, 0.f, 0.f);
}

// ---------------------------------------------------------------------------
// Wt[n][k] = bf16(W[k][n]) : 64 x 512 bf16 (64 KB, L2-resident afterwards)
__global__ void wt_kernel(const float* __restrict__ W, unsigned short* __restrict__ wt) {
    int i = blockIdx.x * blockDim.x + threadIdx.x;
    if (i < D_OUT * K_DIM) {
        int n = i >> 9;        // / 512
        int k = i & 511;
        wt[i] = f32_to_bf16(W[k * D_OUT + n]);
    }
}

// ---------------------------------------------------------------------------
// h = A @ W via bf16 MFMA. Block = 256 thr = 4 waves; wave = 16 rows x 64 cols.
// No LDS. A fragments straight from global fp32 (coalesced 32 B/lane per
// k-step), converted in-register. B fragments from Wt (L2-hot).
__global__ __launch_bounds__(256) void gemm_kernel(
    const float* __restrict__ A, const unsigned short* __restrict__ wt,
    float* __restrict__ H, int n) {
    const int tid  = threadIdx.x;
    const int wv   = tid >> 6;
    const int lane = tid & 63;
    const int ln   = lane & 15;
    const int quad = lane >> 4;           // 0..3
    const int row0 = blockIdx.x * 64 + wv * 16;

    int arow = row0 + ln;
    if (arow >= n) arow = n - 1;          // clamp (stores are guarded)
    const float* Arow = A + (size_t)arow * K_DIM;
    const unsigned short* wb = wt + (size_t)ln * K_DIM;

    floatx4 acc0 = {0.f, 0.f, 0.f, 0.f};
    floatx4 acc1 = {0.f, 0.f, 0.f, 0.f};
    floatx4 acc2 = {0.f, 0.f, 0.f, 0.f};
    floatx4 acc3 = {0.f, 0.f, 0.f, 0.f};

#pragma unroll 4
    for (int ks = 0; ks < K_DIM; ks += 32) {
        const int koff = ks + quad * 8;   // 8 consecutive k per lane
        floatx4 a0 = *reinterpret_cast<const floatx4*>(Arow + koff);
        floatx4 a1 = *reinterpret_cast<const floatx4*>(Arow + koff + 4);
        short8 af;
        af[0] = (short)f32_to_bf16(a0[0]);
        af[1] = (short)f32_to_bf16(a0[1]);
        af[2] = (short)f32_to_bf16(a0[2]);
        af[3] = (short)f32_to_bf16(a0[3]);
        af[4] = (short)f32_to_bf16(a1[0]);
        af[5] = (short)f32_to_bf16(a1[1]);
        af[6] = (short)f32_to_bf16(a1[2]);
        af[7] = (short)f32_to_bf16(a1[3]);
        short8 b0 = *reinterpret_cast<const short8*>(wb + koff);
        short8 b1 = *reinterpret_cast<const short8*>(wb + 16 * K_DIM + koff);
        short8 b2 = *reinterpret_cast<const short8*>(wb + 32 * K_DIM + koff);
        short8 b3 = *reinterpret_cast<const short8*>(wb + 48 * K_DIM + koff);
        acc0 = __builtin_amdgcn_mfma_f32_16x16x32_bf16(af, b0, acc0, 0, 0, 0);
        acc1 = __builtin_amdgcn_mfma_f32_16x16x32_bf16(af, b1, acc1, 0, 0, 0);
        acc2 = __builtin_amdgcn_mfma_f32_16x16x32_bf16(af, b2, acc2, 0, 0, 0);
        acc3 = __builtin_amdgcn_mfma_f32_16x16x32_bf16(af, b3, acc3, 0, 0, 0);
    }

    // C/D layout: col = lane&15, row = quad*4 + reg  [verified m89]
#pragma unroll
    for (int r = 0; r < 4; r++) {
        int gr = row0 + quad * 4 + r;
        if (gr < n) {
            float* Hr = H + (size_t)gr * D_OUT;
            Hr[ln]      = acc0[r];
            Hr[16 + ln] = acc1[r];
            Hr[32 + ln] = acc2[r];
            Hr[48 + ln] = acc3[r];
        }
    }
}

// ---------------------------------------------------------------------------
// Direct COO aggregation: one wave per edge, lane = output column.
// acc[r*64+lane] += v * h[c*64+lane].  Atomics pack 16 lanes/cache-line;
// accumulator (25.6 MB) is L2-resident (3.2 MB/XCD).
__global__ __launch_bounds__(256) void atomic_agg_kernel(
    const float* __restrict__ h, const float* __restrict__ vals,
    const int* __restrict__ rows, const int* __restrict__ cols,
    float* __restrict__ acc, int E) {
    int e = blockIdx.x * 4 + (threadIdx.x >> 6);
    int lane = threadIdx.x & 63;
    if (e >= E) return;
    int r = rows[e];
    int c = cols[e];
    float v = vals[e];
    float m = v * h[(size_t)c * D_OUT + lane];
    atomicAdd(&acc[(size_t)r * D_OUT + lane], m);
}

// ---------------------------------------------------------------------------
// out = relu(acc), float4-vectorized
__global__ void relu_kernel(const float4* __restrict__ acc, float4* __restrict__ out, int n4) {
    int i = blockIdx.x * blockDim.x + threadIdx.x;
    if (i < n4) {
        float4 v = acc[i];
        out[i] = make_float4(fmaxf(v.x, 0.f), fmaxf(v.y, 0.f),
                             fmaxf(v.z, 0.f), fmaxf(v.w, 0.f));
    }
}

// ---------------------------------------------------------------------------
extern "C" void kernel_launch(void* const* d_in, const int* in_sizes, int n_in,
                              void* d_out, int out_size, void* d_ws, size_t ws_size,
                              hipStream_t stream) {
    const float* A    = (const float*)d_in[0];
    const float* W    = (const float*)d_in[1];
    const float* vals = (const float*)d_in[2];
    const int*   rows = (const int*)d_in[3];
    const int*   cols = (const int*)d_in[4];
    float* out = (float*)d_out;

    const int N = out_size / D_OUT;          // 100000
    const int E = in_sizes[2];               // 1600000

    // workspace layout
    char* ws = (char*)d_ws;
    float*          h   = (float*)ws;                                   // N*64 f32
    float*          acc = h + (size_t)N * D_OUT;                        // N*64 f32
    unsigned short* wt  = (unsigned short*)(acc + (size_t)N * D_OUT);   // 64*512 bf16

    const int n4 = N * D_OUT / 4;

    wt_kernel<<<(D_OUT * K_DIM + 255) / 256, 256, 0, stream>>>(W, wt);
    zero4_kernel<<<(n4 + 255) / 256, 256, 0, stream>>>((float4*)acc, n4);
    gemm_kernel<<<(N + 63) / 64, 256, 0, stream>>>(A, wt, h, N);
    atomic_agg_kernel<<<(E + 3) / 4, 256, 0, stream>>>(h, vals, rows, cols, acc, E);
    relu_kernel<<<(n4 + 255) / 256, 256, 0, stream>>>((const float4*)acc, (float4*)out, n4);
}